// Round 3
// baseline (441.962 us; speedup 1.0000x reference)
//
#include <hip/hip_runtime.h>
#include <math.h>

#define NPTS   32768
#define NK     4
#define GRID_  16
#define CIN    64
#define COUT   64
#define NCELLS (NK*GRID_*GRID_*GRID_)     /* 16384 */
#define NENT   (NPTS*8)                   /* 262144 */
#define NENTP  (NENT + NCELLS*15)         /* padded entry capacity: 507904 */
#define CPB    16                         /* cells per block in k_main */

typedef __attribute__((ext_vector_type(8))) short  short8;
typedef __attribute__((ext_vector_type(4))) float  f32x4;

static __device__ inline unsigned short f2bf(float f) {
    unsigned int u = __builtin_bit_cast(unsigned int, f);
    unsigned int r = u + 0x7fff + ((u >> 16) & 1);   // RNE to bf16
    return (unsigned short)(r >> 16);
}

// ---------------------------------------------------------------------------
// Pass 1: histogram of point-corner references per cell
// ---------------------------------------------------------------------------
__global__ void k_hist(const int* __restrict__ pidx, const float* __restrict__ pos,
                       int* __restrict__ hist, int n) {
    int p = blockIdx.x * blockDim.x + threadIdx.x;
    if (p >= n) return;
    int pk = pidx[p];
    float lx = pos[3*p+0]*16.f - 0.5f;
    float ly = pos[3*p+1]*16.f - 0.5f;
    float lz = pos[3*p+2]*16.f - 0.5f;
    int fx = (int)floorf(lx), fy = (int)floorf(ly), fz = (int)floorf(lz);
#pragma unroll
    for (int c = 0; c < 8; ++c) {
        int c0 = c & 1, c1 = (c >> 1) & 1, c2 = (c >> 2) & 1;
        int ix = min(max(fx + c0, 0), GRID_-1);
        int iy = min(max(fy + c1, 0), GRID_-1);
        int iz = min(max(fz + c2, 0), GRID_-1);
        int cell = ((pk*GRID_ + iz)*GRID_ + iy)*GRID_ + ix;
        atomicAdd(&hist[cell], 1);
    }
}

// ---------------------------------------------------------------------------
// Pass 2: unordered CSR allocation, buckets padded to 16 entries so k_main's
// int4/float4 entry loads are 16B-aligned. Wave scan + 1 atomic per wave.
// ---------------------------------------------------------------------------
__global__ void k_alloc(const int* __restrict__ hist, int* __restrict__ offsets,
                        int* __restrict__ cursor, int* __restrict__ gcnt) {
    int i = blockIdx.x * blockDim.x + threadIdx.x;   // 16384 threads
    int l = threadIdx.x & 63;
    int v  = hist[i];
    int vp = (v + 15) & ~15;          // padded size
    int p = vp;
#pragma unroll
    for (int d = 1; d < 64; d <<= 1) {
        int t = __shfl_up(p, d);
        if (l >= d) p += t;
    }
    int total = __shfl(p, 63);
    int base = 0;
    if (l == 63) base = atomicAdd(gcnt, total);
    base = __shfl(base, 63);
    int off = base + p - vp;          // exclusive prefix, 16-aligned
    offsets[i] = off;
    cursor[i]  = off;
}

// ---------------------------------------------------------------------------
// Pass 3: scatter (point_id, weight) entries into per-cell CSR buckets
// ---------------------------------------------------------------------------
__global__ void k_scatter(const int* __restrict__ pidx, const float* __restrict__ pos,
                          int* __restrict__ cursor, int* __restrict__ epid,
                          float* __restrict__ ew, int n) {
    int p = blockIdx.x * blockDim.x + threadIdx.x;
    if (p >= n) return;
    int pk = pidx[p];
    float lx = pos[3*p+0]*16.f - 0.5f;
    float ly = pos[3*p+1]*16.f - 0.5f;
    float lz = pos[3*p+2]*16.f - 0.5f;
    float flx = floorf(lx), fly = floorf(ly), flz = floorf(lz);
    int fx = (int)flx, fy = (int)fly, fz = (int)flz;
    float tx = lx - flx, ty = ly - fly, tz = lz - flz;
    float wx[2] = {1.f - tx, tx};
    float wy[2] = {1.f - ty, ty};
    float wz[2] = {1.f - tz, tz};
#pragma unroll
    for (int c = 0; c < 8; ++c) {
        int c0 = c & 1, c1 = (c >> 1) & 1, c2 = (c >> 2) & 1;
        int ix = min(max(fx + c0, 0), GRID_-1);
        int iy = min(max(fy + c1, 0), GRID_-1);
        int iz = min(max(fz + c2, 0), GRID_-1);
        int cell = ((pk*GRID_ + iz)*GRID_ + iy)*GRID_ + ix;
        float w = wx[c0] * wy[c1] * wz[c2];
        int e = atomicAdd(&cursor[cell], 1);
        epid[e] = p;
        ew[e]   = w;
    }
}

// ---------------------------------------------------------------------------
// Pass 4: 1024 persistent blocks x 16 cells. Double-buffered K staging via
// global_load_lds_dwordx4 (fp32, 16 KB/cell); DMA for cell i+1 overlaps cell
// i's body; ONE __syncthreads per cell. B-fragments converted fp32->bf16 in
// register once per cell. A-fragments gathered straight from global xs (no
// LDS round-trip, no per-batch barriers). Epilogue: 4 HW fp32 atomics/lane.
//
// MFMA 16x16x32_bf16 layouts (m89/m120-verified):
//   A[m][k]: m=lane&15, k=(lane>>4)*8+j ; B[k][n]: n=lane&15, k=(lane>>4)*8+j
//   D[m][n]: n=lane&15, m=(lane>>4)*4+reg
// ---------------------------------------------------------------------------
__global__ __launch_bounds__(256)
void k_main(const float* __restrict__ xs, const float* __restrict__ kernels,
            const float* __restrict__ biases, const int* __restrict__ offsets,
            const int* __restrict__ hist, const int* __restrict__ epid,
            const float* __restrict__ ew, float* __restrict__ out) {
    __shared__ float Ks[2][CIN * COUT];   // 2 x 16 KB
    int tid = threadIdx.x;
    int l   = tid & 63;       // lane
    int wv  = tid >> 6;       // wave 0..3 -> cout chunk
    int m16 = l & 15;
    int q   = l >> 4;
    int cell0 = blockIdx.x * CPB;
    int ncol  = wv * 16 + m16;

    // prologue: DMA cell0 -> buf0
    {
        const float* Kg = kernels + (size_t)cell0 * (CIN * COUT);
#pragma unroll
        for (int r = 0; r < 4; ++r) {
            int off = ((r * 4 + wv) * 64 + l) * 4;   // float index, lane-contig 16B
            __builtin_amdgcn_global_load_lds(
                (const __attribute__((address_space(1))) void*)(Kg + off),
                (__attribute__((address_space(3))) void*)(&Ks[0][off]), 16, 0, 0);
        }
    }

    for (int ci = 0; ci < CPB; ++ci) {
        int cur = ci & 1;
        // barrier: (a) drains this wave's DMA for buf[cur] (vmcnt0), so all
        // portions are visible; (b) all waves done reading buf[1-cur].
        __syncthreads();
        if (ci + 1 < CPB) {   // DMA next cell into the buffer just released
            const float* Kg = kernels + (size_t)(cell0 + ci + 1) * (CIN * COUT);
#pragma unroll
            for (int r = 0; r < 4; ++r) {
                int off = ((r * 4 + wv) * 64 + l) * 4;
                __builtin_amdgcn_global_load_lds(
                    (const __attribute__((address_space(1))) void*)(Kg + off),
                    (__attribute__((address_space(3))) void*)(&Ks[1 - cur][off]), 16, 0, 0);
            }
        }
        int cell = cell0 + ci;
        int cnt  = hist[cell];
        if (cnt == 0) continue;
        int start = offsets[cell];

        // B-fragments: 16 ds_read_b32 (4-way bank alias) + cvt, once per cell
        short8 Bf0, Bf1;
#pragma unroll
        for (int j = 0; j < 8; ++j) {
            Bf0[j] = (short)f2bf(Ks[cur][(q * 8 + j) * COUT + ncol]);
            Bf1[j] = (short)f2bf(Ks[cur][(32 + q * 8 + j) * COUT + ncol]);
        }
        float bias_c = biases[(size_t)cell * COUT + ncol];

        int nb = (cnt + 15) >> 4;
        for (int b = 0; b < nb; ++b) {
            int ebase = start + (b << 4);
            // ---- A fragment: row m16 of this batch, k-chunk q ----
            int pidA = epid[ebase + m16] & (NPTS - 1);   // clamp pad garbage
            const float* xr = xs + (size_t)pidA * CIN + q * 8;
            float4 a0 = *(const float4*)(xr);
            float4 a1 = *(const float4*)(xr + 4);
            float4 a2 = *(const float4*)(xr + 32);
            float4 a3 = *(const float4*)(xr + 36);
            short8 af0, af1;
            af0[0]=(short)f2bf(a0.x); af0[1]=(short)f2bf(a0.y);
            af0[2]=(short)f2bf(a0.z); af0[3]=(short)f2bf(a0.w);
            af0[4]=(short)f2bf(a1.x); af0[5]=(short)f2bf(a1.y);
            af0[6]=(short)f2bf(a1.z); af0[7]=(short)f2bf(a1.w);
            af1[0]=(short)f2bf(a2.x); af1[1]=(short)f2bf(a2.y);
            af1[2]=(short)f2bf(a2.z); af1[3]=(short)f2bf(a2.w);
            af1[4]=(short)f2bf(a3.x); af1[5]=(short)f2bf(a3.y);
            af1[6]=(short)f2bf(a3.z); af1[7]=(short)f2bf(a3.w);

            f32x4 acc = {0.f, 0.f, 0.f, 0.f};
            acc = __builtin_amdgcn_mfma_f32_16x16x32_bf16(af0, Bf0, acc, 0, 0, 0);
            acc = __builtin_amdgcn_mfma_f32_16x16x32_bf16(af1, Bf1, acc, 0, 0, 0);

            // ---- epilogue: rows q*4..q*4+3, aligned int4/float4 loads ----
            int erow = ebase + (q << 2);
            int4   pe = *(const int4*)&epid[erow];
            float4 we = *(const float4*)&ew[erow];
            int rem = cnt - (b << 4) - (q << 2);   // valid rows in this quad
            if (rem > 0) {
                unsafeAtomicAdd(&out[(size_t)(pe.x) * COUT + ncol], we.x * (acc[0] + bias_c));
                if (rem > 1) unsafeAtomicAdd(&out[(size_t)(pe.y) * COUT + ncol], we.y * (acc[1] + bias_c));
                if (rem > 2) unsafeAtomicAdd(&out[(size_t)(pe.z) * COUT + ncol], we.z * (acc[2] + bias_c));
                if (rem > 3) unsafeAtomicAdd(&out[(size_t)(pe.w) * COUT + ncol], we.w * (acc[3] + bias_c));
            }
        }
    }
}

// ---------------------------------------------------------------------------
extern "C" void kernel_launch(void* const* d_in, const int* in_sizes, int n_in,
                              void* d_out, int out_size, void* d_ws, size_t ws_size,
                              hipStream_t stream) {
    const int*   pidx    = (const int*)  d_in[0];
    const float* pos     = (const float*)d_in[1];
    const float* xs      = (const float*)d_in[2];
    const float* kernels = (const float*)d_in[3];
    const float* biases  = (const float*)d_in[4];
    float*       out     = (float*)d_out;
    int n = in_sizes[0];   // 32768

    // ws ints: hist[16384] | gcnt(16) | offsets[16384] | cursor[16384]
    //          | epid[507904] | ew[507904]   (~4.2 MB)
    int* ws      = (int*)d_ws;
    int* hist    = ws;
    int* gcnt    = ws + NCELLS;
    int* offsets = ws + NCELLS + 16;
    int* cursor  = offsets + NCELLS;
    int* epid    = cursor + NCELLS;
    float* ew    = (float*)(epid + NENTP);

    hipMemsetAsync(hist, 0, (NCELLS + 16) * sizeof(int), stream);
    hipMemsetAsync(d_out, 0, (size_t)out_size * sizeof(float), stream);

    int blocks = (n + 255) / 256;
    k_hist   <<<blocks,       256, 0, stream>>>(pidx, pos, hist, n);
    k_alloc  <<<NCELLS / 256, 256, 0, stream>>>(hist, offsets, cursor, gcnt);
    k_scatter<<<blocks,       256, 0, stream>>>(pidx, pos, cursor, epid, ew, n);
    k_main   <<<NCELLS / CPB, 256, 0, stream>>>(xs, kernels, biases, offsets,
                                                hist, epid, ew, out);
}

// Round 4
// 431.020 us; speedup vs baseline: 1.0254x; 1.0254x over previous
//
#include <hip/hip_runtime.h>
#include <math.h>

#define NPTS   32768
#define NK     4
#define GRID_  16
#define CIN    64
#define COUT   64
#define NCELLS (NK*GRID_*GRID_*GRID_)     /* 16384 */
#define NENT   (NPTS*8)                   /* 262144, power of 2 */
#define NENTP  (NENT + NCELLS*15)         /* padded CSR capacity: 507904 */

typedef __attribute__((ext_vector_type(8))) short  short8;
typedef __attribute__((ext_vector_type(4))) float  f32x4;

static __device__ inline unsigned short f2bf(float f) {
    unsigned int u = __builtin_bit_cast(unsigned int, f);
    unsigned int r = u + 0x7fff + ((u >> 16) & 1);   // RNE to bf16
    return (unsigned short)(r >> 16);
}

// ---------------------------------------------------------------------------
// Pass 1: histogram of point-corner references per cell
// ---------------------------------------------------------------------------
__global__ void k_hist(const int* __restrict__ pidx, const float* __restrict__ pos,
                       int* __restrict__ hist, int n) {
    int p = blockIdx.x * blockDim.x + threadIdx.x;
    if (p >= n) return;
    int pk = pidx[p];
    float lx = pos[3*p+0]*16.f - 0.5f;
    float ly = pos[3*p+1]*16.f - 0.5f;
    float lz = pos[3*p+2]*16.f - 0.5f;
    int fx = (int)floorf(lx), fy = (int)floorf(ly), fz = (int)floorf(lz);
#pragma unroll
    for (int c = 0; c < 8; ++c) {
        int c0 = c & 1, c1 = (c >> 1) & 1, c2 = (c >> 2) & 1;
        int ix = min(max(fx + c0, 0), GRID_-1);
        int iy = min(max(fy + c1, 0), GRID_-1);
        int iz = min(max(fz + c2, 0), GRID_-1);
        int cell = ((pk*GRID_ + iz)*GRID_ + iy)*GRID_ + ix;
        atomicAdd(&hist[cell], 1);
    }
}

// ---------------------------------------------------------------------------
// Pass 2: unordered CSR allocation, buckets padded to 16 entries (aligned
// int4 loads in k_main). Wave scan + 1 global atomic per wave.
// ---------------------------------------------------------------------------
__global__ void k_alloc(const int* __restrict__ hist, int* __restrict__ offsets,
                        int* __restrict__ cursor, int* __restrict__ gcnt) {
    int i = blockIdx.x * blockDim.x + threadIdx.x;   // 16384 threads
    int l = threadIdx.x & 63;
    int v  = hist[i];
    int vp = (v + 15) & ~15;
    int p = vp;
#pragma unroll
    for (int d = 1; d < 64; d <<= 1) {
        int t = __shfl_up(p, d);
        if (l >= d) p += t;
    }
    int total = __shfl(p, 63);
    int base = 0;
    if (l == 63) base = atomicAdd(gcnt, total);
    base = __shfl(base, 63);
    offsets[i] = base + p - vp;
    cursor[i]  = base + p - vp;
}

// ---------------------------------------------------------------------------
// Pass 3: scatter entry ids (eid = p*8+c) into per-cell CSR buckets; store
// trilinear weight dense at ew[eid].
// ---------------------------------------------------------------------------
__global__ void k_scatter(const int* __restrict__ pidx, const float* __restrict__ pos,
                          int* __restrict__ cursor, int* __restrict__ ebuf,
                          float* __restrict__ ew, int n) {
    int p = blockIdx.x * blockDim.x + threadIdx.x;
    if (p >= n) return;
    int pk = pidx[p];
    float lx = pos[3*p+0]*16.f - 0.5f;
    float ly = pos[3*p+1]*16.f - 0.5f;
    float lz = pos[3*p+2]*16.f - 0.5f;
    float flx = floorf(lx), fly = floorf(ly), flz = floorf(lz);
    int fx = (int)flx, fy = (int)fly, fz = (int)flz;
    float tx = lx - flx, ty = ly - fly, tz = lz - flz;
    float wx[2] = {1.f - tx, tx};
    float wy[2] = {1.f - ty, ty};
    float wz[2] = {1.f - tz, tz};
#pragma unroll
    for (int c = 0; c < 8; ++c) {
        int c0 = c & 1, c1 = (c >> 1) & 1, c2 = (c >> 2) & 1;
        int ix = min(max(fx + c0, 0), GRID_-1);
        int iy = min(max(fy + c1, 0), GRID_-1);
        int iz = min(max(fz + c2, 0), GRID_-1);
        int cell = ((pk*GRID_ + iz)*GRID_ + iy)*GRID_ + ix;
        ew[p * 8 + c] = wx[c0] * wy[c1] * wz[c2];
        int e = atomicAdd(&cursor[cell], 1);
        ebuf[e] = p * 8 + c;
    }
}

// ---------------------------------------------------------------------------
// Pass 4 (phase A): one block per cell. K staged fp32 via global_load_lds
// (16 KB DMA, no VGPR round-trip); B-frags converted fp32->bf16 in register
// once per cell. Batches of 16 entries: cooperative coalesced X staging to
// LDS (bf16, padded stride), 2x mfma_f32_16x16x32_bf16, then NON-ATOMIC
// stores of (dot + bias) rows to res[eid*64 + ncol]. Zero output atomics.
//
// MFMA 16x16x32_bf16 layouts (m89/m120-verified):
//   A[m][k]: m=lane&15, k=(lane>>4)*8+j ; B[k][n]: n=lane&15, k=(lane>>4)*8+j
//   D[m][n]: n=lane&15, m=(lane>>4)*4+reg
// ---------------------------------------------------------------------------
__global__ __launch_bounds__(256)
void k_main(const float* __restrict__ xs, const float* __restrict__ kernels,
            const float* __restrict__ biases, const int* __restrict__ offsets,
            const int* __restrict__ hist, const int* __restrict__ ebuf,
            float* __restrict__ res) {
    __shared__ float Ks[CIN * COUT];        // 16 KB fp32, row-major [k][n]
    __shared__ unsigned short Xb[16 * 72];  // batch A rows (bf16), padded stride
    __shared__ int eB[16];                  // eids of this batch

    int cell = blockIdx.x;
    int cnt  = hist[cell];
    if (cnt == 0) return;
    int start = offsets[cell];

    int tid = threadIdx.x;
    int l   = tid & 63;
    int wv  = tid >> 6;
    int m16 = l & 15;
    int q   = l >> 4;
    int ncol = wv * 16 + m16;

    // ---- DMA K block into LDS (fp32, lane-contiguous 16B per lane) ----
    const float* Kg = kernels + (size_t)cell * (CIN * COUT);
#pragma unroll
    for (int r = 0; r < 4; ++r) {
        int off = ((r * 4 + wv) * 64 + l) * 4;   // float index
        __builtin_amdgcn_global_load_lds(
            (const __attribute__((address_space(1))) void*)(Kg + off),
            (__attribute__((address_space(3))) void*)(&Ks[off]), 16, 0, 0);
    }
    float bias_c = biases[(size_t)cell * COUT + ncol];
    __syncthreads();   // drains DMA (vmcnt0) + all waves ready

    // ---- loop-invariant B-fragments, fp32 LDS -> bf16 regs ----
    short8 Bf0, Bf1;
#pragma unroll
    for (int j = 0; j < 8; ++j) {
        Bf0[j] = (short)f2bf(Ks[(q * 8 + j) * COUT + ncol]);
        Bf1[j] = (short)f2bf(Ks[(32 + q * 8 + j) * COUT + ncol]);
    }

    int nb = (cnt + 15) >> 4;
    for (int b = 0; b < nb; ++b) {
        int ebase = start + (b << 4);
        {   // cooperative X staging: thread t -> row t>>4, channels (t&15)*4..+3
            int row = tid >> 4;
            int c4  = (tid & 15) << 2;
            int eid = ebuf[ebase + row] & (NENT - 1);   // clamp pad garbage
            int pid = eid >> 3;
            float4 xv = *(const float4*)&xs[(size_t)pid * CIN + c4];
            ushort4 xb = { f2bf(xv.x), f2bf(xv.y), f2bf(xv.z), f2bf(xv.w) };
            *(ushort4*)&Xb[row * 72 + c4] = xb;
            if (tid < 16) eB[tid] = ebuf[ebase + tid] & (NENT - 1);
        }
        __syncthreads();

        f32x4 acc = {0.f, 0.f, 0.f, 0.f};
        {
            const short8 af0 = *(const short8*)&Xb[m16 * 72 + q * 8];
            const short8 af1 = *(const short8*)&Xb[m16 * 72 + 32 + q * 8];
            acc = __builtin_amdgcn_mfma_f32_16x16x32_bf16(af0, Bf0, acc, 0, 0, 0);
            acc = __builtin_amdgcn_mfma_f32_16x16x32_bf16(af1, Bf1, acc, 0, 0, 0);
        }

        int valid = cnt - (b << 4);                  // # real rows this batch
#pragma unroll
        for (int reg = 0; reg < 4; ++reg) {
            int row = (q << 2) + reg;                // D row = batch row
            if (row < valid) {
                int eid = eB[row];
                res[(size_t)eid * COUT + ncol] = acc[reg] + bias_c;
            }
        }
        __syncthreads();                             // before Xb/eB overwrite
    }
}

// ---------------------------------------------------------------------------
// Pass 5 (phase B): gather-reduce. 16 points/block; 16 threads/point; each
// thread owns 4 channels (float4). res rows for a point are 8 contiguous
// 256B rows -> fully coalesced. out = sum_c w_c * res[8p+c].
// ---------------------------------------------------------------------------
__global__ __launch_bounds__(256)
void k_final(const float* __restrict__ res, const float* __restrict__ ew,
             float* __restrict__ out, int n) {
    int tid = threadIdx.x;
    int p   = blockIdx.x * 16 + (tid >> 4);
    if (p >= n) return;
    int c4  = (tid & 15) << 2;
    f32x4 acc = {0.f, 0.f, 0.f, 0.f};
#pragma unroll
    for (int c = 0; c < 8; ++c) {
        float w = ew[p * 8 + c];
        const float4 r = *(const float4*)&res[(size_t)(p * 8 + c) * COUT + c4];
        acc[0] = fmaf(w, r.x, acc[0]);
        acc[1] = fmaf(w, r.y, acc[1]);
        acc[2] = fmaf(w, r.z, acc[2]);
        acc[3] = fmaf(w, r.w, acc[3]);
    }
    *(float4*)&out[(size_t)p * COUT + c4] = *(float4*)&acc;
}

// ---------------------------------------------------------------------------
extern "C" void kernel_launch(void* const* d_in, const int* in_sizes, int n_in,
                              void* d_out, int out_size, void* d_ws, size_t ws_size,
                              hipStream_t stream) {
    const int*   pidx    = (const int*)  d_in[0];
    const float* pos     = (const float*)d_in[1];
    const float* xs      = (const float*)d_in[2];
    const float* kernels = (const float*)d_in[3];
    const float* biases  = (const float*)d_in[4];
    float*       out     = (float*)d_out;
    int n = in_sizes[0];   // 32768

    // ws ints: hist[16384] | gcnt(16) | offsets[16384] | cursor[16384]
    //          | ebuf[507904] | ew[262144] | res[262144*64]  (~70 MB)
    int* ws      = (int*)d_ws;
    int* hist    = ws;
    int* gcnt    = ws + NCELLS;
    int* offsets = ws + NCELLS + 16;
    int* cursor  = offsets + NCELLS;
    int* ebuf    = cursor + NCELLS;
    float* ew    = (float*)(ebuf + NENTP);
    float* res   = ew + NENT;

    hipMemsetAsync(hist, 0, (NCELLS + 16) * sizeof(int), stream);

    int blocks = (n + 255) / 256;
    k_hist   <<<blocks,       256, 0, stream>>>(pidx, pos, hist, n);
    k_alloc  <<<NCELLS / 256, 256, 0, stream>>>(hist, offsets, cursor, gcnt);
    k_scatter<<<blocks,       256, 0, stream>>>(pidx, pos, cursor, ebuf, ew, n);
    k_main   <<<NCELLS,       256, 0, stream>>>(xs, kernels, biases, offsets,
                                                hist, ebuf, res);
    k_final  <<<(n + 15) / 16, 256, 0, stream>>>(res, ew, out, n);
}